// Round 4
// baseline (1620.768 us; speedup 1.0000x reference)
//
#include <hip/hip_runtime.h>
#include <hip/hip_bf16.h>
#include <math.h>

// ---------------------------------------------------------------------------
// Round 3: attn3 = LDS-resident-K flash attention, one block per (b,h),
// 6 concurrent q-tiles per wave (K-frag reads amortized 6x), 58KB LDS ->
// 2 blocks/CU. K HBM traffic 1x per block (R2's attn2 was HBM-bound at
// 252MB/dispatch from 6-way block split). GEMM path unchanged from R2.
// ws layout unchanged (191,365,120 B).
// ---------------------------------------------------------------------------

using bf16 = __hip_bfloat16;
typedef __attribute__((ext_vector_type(8))) short frag8;
typedef __attribute__((ext_vector_type(4))) float f32x4;

static __device__ __forceinline__ float wave_sum64(float v){
  #pragma unroll
  for (int o = 32; o >= 1; o >>= 1) v += __shfl_xor(v, o, 64);
  return v;
}

static __device__ __forceinline__ void gl_lds16(const bf16* g, bf16* l){
  __builtin_amdgcn_global_load_lds((const __attribute__((address_space(1))) void*)g,
                                   (__attribute__((address_space(3))) void*)l, 16, 0, 0);
}

static __device__ __forceinline__ unsigned pack2(float a, float b){
  union { bf16 h[2]; unsigned u; } u;
  u.h[0] = __float2bfloat16(a); u.h[1] = __float2bfloat16(b);
  return u.u;
}

// dst[n*K+k] = (bf16) src[k*N+n]
__global__ __launch_bounds__(256) void cvt_transpose(bf16* __restrict__ dst,
                                                     const float* __restrict__ src,
                                                     int K, int N){
  int idx = blockIdx.x * 256 + threadIdx.x;
  if (idx >= K * N) return;
  int n = idx / K, k = idx - n * K;
  dst[idx] = __float2bfloat16(src[(size_t)k * N + n]);
}

// embed + PE + scale -> x (bf16), LN1 -> xn (bf16). one wave/row, grid 23040.
__global__ __launch_bounds__(256) void embed_ln1(
    const int* __restrict__ src, const float* __restrict__ emb,
    const float* __restrict__ na, const float* __restrict__ nb,
    bf16* __restrict__ x, bf16* __restrict__ xn)
{
  int row  = blockIdx.x * 4 + (threadIdx.x >> 6);
  int lane = threadIdx.x & 63;
  int s = row % 360;
  int tok = src[row];
  float4 v = *(const float4*)(emb + (size_t)tok * 256 + lane * 4);
  float vv[4] = {v.x, v.y, v.z, v.w};
  if (s < 340){
    const float C = (-2.0f / 256.0f) * 13.287712379549449f;  // -2/D * log2(10000)
    #pragma unroll
    for (int t = 0; t < 4; t++){
      int c = lane * 4 + t;
      float ang = (float)s * exp2f(C * (float)c);
      float pe = (c & 1) ? cosf(ang) : sinf(ang);
      vv[t] = 16.0f * vv[t] + pe;
    }
  }
  float sum = wave_sum64(vv[0] + vv[1] + vv[2] + vv[3]);
  float mu = sum * (1.0f / 256.0f);
  float d0 = vv[0]-mu, d1 = vv[1]-mu, d2 = vv[2]-mu, d3 = vv[3]-mu;
  float sq = wave_sum64(d0*d0 + d1*d1 + d2*d2 + d3*d3);
  float inv = 1.0f / (sqrtf(sq * (1.0f / 255.0f)) + 1e-6f);
  bf16 xo[4] = { __float2bfloat16(vv[0]), __float2bfloat16(vv[1]),
                 __float2bfloat16(vv[2]), __float2bfloat16(vv[3]) };
  *(uint2*)(x + (size_t)row * 256 + lane * 4) = *(uint2*)xo;
  float4 a4 = *(const float4*)(na + lane * 4);
  float4 b4 = *(const float4*)(nb + lane * 4);
  bf16 o4[4] = { __float2bfloat16(a4.x * d0 * inv + b4.x),
                 __float2bfloat16(a4.y * d1 * inv + b4.y),
                 __float2bfloat16(a4.z * d2 * inv + b4.z),
                 __float2bfloat16(a4.w * d3 * inv + b4.w) };
  *(uint2*)(xn + (size_t)row * 256 + lane * 4) = *(uint2*)o4;
}

// LN over bf16 x -> bf16 xn. one wave per row. grid 23040.
__global__ __launch_bounds__(256) void ln_k(
    const bf16* __restrict__ x, const float* __restrict__ na,
    const float* __restrict__ nb, bf16* __restrict__ xn)
{
  int row  = blockIdx.x * 4 + (threadIdx.x >> 6);
  int lane = threadIdx.x & 63;
  uint2 raw = *(const uint2*)(x + (size_t)row * 256 + lane * 4);
  bf16* xr = (bf16*)&raw;
  float v0 = __bfloat162float(xr[0]), v1 = __bfloat162float(xr[1]);
  float v2 = __bfloat162float(xr[2]), v3 = __bfloat162float(xr[3]);
  float sum = wave_sum64(v0 + v1 + v2 + v3);
  float mu = sum * (1.0f / 256.0f);
  float d0 = v0-mu, d1 = v1-mu, d2 = v2-mu, d3 = v3-mu;
  float sq = wave_sum64(d0*d0 + d1*d1 + d2*d2 + d3*d3);
  float inv = 1.0f / (sqrtf(sq * (1.0f / 255.0f)) + 1e-6f);
  float4 a4 = *(const float4*)(na + lane * 4);
  float4 b4 = *(const float4*)(nb + lane * 4);
  bf16 o4[4] = { __float2bfloat16(a4.x * d0 * inv + b4.x),
                 __float2bfloat16(a4.y * d1 * inv + b4.y),
                 __float2bfloat16(a4.z * d2 * inv + b4.z),
                 __float2bfloat16(a4.w * d3 * inv + b4.w) };
  *(uint2*)(xn + (size_t)row * 256 + lane * 4) = *(uint2*)o4;
}

// C = A[M][K] @ Bt[N][K]^T + bias. 128x128 tile, BK=32, global_load_lds staging.
// MODE 2: relu, bf16 row-major [M][N]
// MODE 3: bf16 residual in-place: xres[m*256+n] += acc (+bias)
// MODE 4: merged QKV epilogue (N=768): n<256 q-layout, <512 k-layout, else v^T
template<int MODE>
__global__ __launch_bounds__(256) void gemm_bt(
    const bf16* __restrict__ A, int lda,
    const bf16* __restrict__ Bt, int ldb,
    const float* __restrict__ bias,
    bf16* __restrict__ outb, bf16* __restrict__ xres,
    int N, int K,
    const float* __restrict__ bq, const float* __restrict__ bk,
    const float* __restrict__ bv)
{
  __shared__ bf16 As[128 * 32];
  __shared__ bf16 Bs[128 * 32];
  int m0 = blockIdx.x * 128, n0 = blockIdx.y * 128;
  int tid = threadIdx.x;
  int wave = tid >> 6, lane = tid & 63;
  int wm = (wave >> 1) * 64, wn = (wave & 1) * 64;
  int r = lane & 15, qd = lane >> 4;

  int slot0 = wave * 128 + lane;
  int row0 = slot0 >> 2, c0 = slot0 & 3;
  int row1 = (slot0 + 64) >> 2, c1 = (slot0 + 64) & 3;
  const bf16* ag0 = A  + (size_t)(m0 + row0) * lda + c0 * 8;
  const bf16* ag1 = A  + (size_t)(m0 + row1) * lda + c1 * 8;
  const bf16* bg0 = Bt + (size_t)(n0 + row0) * ldb + c0 * 8;
  const bf16* bg1 = Bt + (size_t)(n0 + row1) * ldb + c1 * 8;
  bf16* lA0 = As + (size_t)(wave * 128) * 8;
  bf16* lA1 = As + (size_t)(wave * 128 + 64) * 8;
  bf16* lB0 = Bs + (size_t)(wave * 128) * 8;
  bf16* lB1 = Bs + (size_t)(wave * 128 + 64) * 8;

  f32x4 acc[4][4];
  #pragma unroll
  for (int mt = 0; mt < 4; mt++)
    #pragma unroll
    for (int nt = 0; nt < 4; nt++) acc[mt][nt] = (f32x4){0.f, 0.f, 0.f, 0.f};

  for (int k0 = 0; k0 < K; k0 += 32){
    gl_lds16(ag0, lA0); gl_lds16(ag1, lA1);
    gl_lds16(bg0, lB0); gl_lds16(bg1, lB1);
    ag0 += 32; ag1 += 32; bg0 += 32; bg1 += 32;
    __syncthreads();
    frag8 af[4], bfr[4];
    #pragma unroll
    for (int t = 0; t < 4; t++){
      af[t]  = *(const frag8*)(As + (wm + t * 16 + r) * 32 + qd * 8);
      bfr[t] = *(const frag8*)(Bs + (wn + t * 16 + r) * 32 + qd * 8);
    }
    #pragma unroll
    for (int mt = 0; mt < 4; mt++)
      #pragma unroll
      for (int nt = 0; nt < 4; nt++)
        acc[mt][nt] = __builtin_amdgcn_mfma_f32_16x16x32_bf16(af[mt], bfr[nt], acc[mt][nt], 0, 0, 0);
    __syncthreads();
  }

  #pragma unroll
  for (int mt = 0; mt < 4; mt++)
    #pragma unroll
    for (int nt = 0; nt < 4; nt++)
      #pragma unroll
      for (int i = 0; i < 4; i++){
        int m = m0 + wm + mt * 16 + qd * 4 + i;
        int n = n0 + wn + nt * 16 + r;
        float v = acc[mt][nt][i];
        if (MODE == 2){
          v += bias[n];
          v = fmaxf(v, 0.0f);
          outb[(size_t)m * N + n] = __float2bfloat16(v);
        } else if (MODE == 3){
          if (bias) v += bias[n];
          size_t o = (size_t)m * 256 + n;
          xres[o] = __float2bfloat16(__bfloat162float(xres[o]) + v);
        } else {  // MODE 4
          int region = n >> 8, nn = n & 255;
          int h = nn >> 6, dk = nn & 63;
          v += (region == 0 ? bq : region == 1 ? bk : bv)[nn];
          int b = m / 360, s = m - b * 360;
          if (region < 2){
            size_t off = (((size_t)(b * 4 + h) * 360 + s) << 6) + dk;
            outb[off + (size_t)region * 11796480] = __float2bfloat16(v);
          } else {
            outb[23592960 + ((size_t)((b * 4 + h) * 64 + dk)) * 360 + s] = __float2bfloat16(v);
          }
        }
      }
}

// attn3: one block per (b_local,h) [512 blocks/half], 4 waves.
// K in LDS (360x72 pad, uniform banks). Each wave: 6 concurrent q-tiles
// (accO[6][4], qa[6]), 2-pass softmax; P via 16x48 per-wave LDS; V from global.
__global__ __launch_bounds__(256, 2) void attn3(
    const bf16* __restrict__ q, const bf16* __restrict__ kk, const bf16* __restrict__ vt,
    const int* __restrict__ src, bf16* __restrict__ ctx)
{
  __shared__ bf16 Ks[360][72];
  __shared__ bf16 Pb[4][16][48];
  int bh = blockIdx.x;
  int b = bh >> 2, h = bh & 3;
  int wave = threadIdx.x >> 6, lane = threadIdx.x & 63;
  int r = lane & 15, qd = lane >> 4;
  const bf16* qb = q  + (size_t)bh * 360 * 64;
  const bf16* kb = kk + (size_t)bh * 360 * 64;
  const bf16* vb = vt + (size_t)bh * 64 * 360;
  const int* srow = src + b * 360;

  // cooperative K -> LDS (once)
  for (int c = threadIdx.x; c < 2880; c += 256){
    int row = c >> 3, g = c & 7;
    *(uint4*)(&Ks[row][g * 8]) = *(const uint4*)(kb + row * 64 + g * 8);
  }
  __syncthreads();

  int ntile = (wave < 3) ? 6 : 5;        // waves 0-2: tiles w*6..w*6+5; wave 3: 18..22
  frag8 qa0[6], qa1[6];
  bool qp[6];
  float mrun[6], lsum[6];
  f32x4 accO[6][4];
  #pragma unroll
  for (int tl = 0; tl < 6; tl++){
    mrun[tl] = -INFINITY; lsum[tl] = 0.f;
    #pragma unroll
    for (int dt = 0; dt < 4; dt++) accO[tl][dt] = (f32x4){0.f, 0.f, 0.f, 0.f};
    qp[tl] = false;
  }
  for (int tl = 0; tl < ntile; tl++){
    int qt = wave * 6 + tl;
    int qg = qt * 16 + r, qrow = qg > 359 ? 359 : qg;
    qa0[tl] = *(const frag8*)(qb + qrow * 64 + qd * 8);
    qa1[tl] = *(const frag8*)(qb + qrow * 64 + 32 + qd * 8);
    qp[tl] = (qg < 360) && (srow[qg] == 799);   // reference masks PAD *queries*
  }

  // ---- pass 1: row max; K-frag LDS reads shared across 6 tiles ----
  for (int kt = 0; kt < 23; kt++){
    int krow = kt * 16 + r; if (krow > 359) krow = 359;
    frag8 kf0 = *(const frag8*)(&Ks[krow][qd * 8]);
    frag8 kf1 = *(const frag8*)(&Ks[krow][32 + qd * 8]);
    for (int tl = 0; tl < ntile; tl++){
      f32x4 z = {0.f, 0.f, 0.f, 0.f};
      z = __builtin_amdgcn_mfma_f32_16x16x32_bf16(kf0, qa0[tl], z, 0, 0, 0);  // C[key][query=r]
      z = __builtin_amdgcn_mfma_f32_16x16x32_bf16(kf1, qa1[tl], z, 0, 0, 0);
      #pragma unroll
      for (int i = 0; i < 4; i++){
        int key = kt * 16 + qd * 4 + i;
        float s = z[i] * 0.125f;
        if (qp[tl]) s = -1.0e9f;
        if (key >= 360) s = -INFINITY;
        mrun[tl] = fmaxf(mrun[tl], s);
      }
    }
  }
  #pragma unroll
  for (int tl = 0; tl < 6; tl++){
    mrun[tl] = fmaxf(mrun[tl], __shfl_xor(mrun[tl], 16, 64));
    mrun[tl] = fmaxf(mrun[tl], __shfl_xor(mrun[tl], 32, 64));
  }

  // ---- pass 2: exp + P->LDS(A-frag) + PV ----
  for (int kc = 0; kc < 12; kc++){
    int krow0 = kc * 32 + r;      if (krow0 > 359) krow0 = 359;
    int krow1 = kc * 32 + 16 + r; if (krow1 > 359) krow1 = 359;
    frag8 kf00 = *(const frag8*)(&Ks[krow0][qd * 8]);
    frag8 kf01 = *(const frag8*)(&Ks[krow0][32 + qd * 8]);
    frag8 kf10 = *(const frag8*)(&Ks[krow1][qd * 8]);
    frag8 kf11 = *(const frag8*)(&Ks[krow1][32 + qd * 8]);
    frag8 vf[4];
    #pragma unroll
    for (int dt = 0; dt < 4; dt++)
      vf[dt] = *(const frag8*)(vb + (size_t)(dt * 16 + r) * 360 + kc * 32 + qd * 8);

    for (int tl = 0; tl < ntile; tl++){
      f32x4 z0 = {0.f, 0.f, 0.f, 0.f}, z1 = {0.f, 0.f, 0.f, 0.f};
      z0 = __builtin_amdgcn_mfma_f32_16x16x32_bf16(kf00, qa0[tl], z0, 0, 0, 0);
      z0 = __builtin_amdgcn_mfma_f32_16x16x32_bf16(kf01, qa1[tl], z0, 0, 0, 0);
      z1 = __builtin_amdgcn_mfma_f32_16x16x32_bf16(kf10, qa0[tl], z1, 0, 0, 0);
      z1 = __builtin_amdgcn_mfma_f32_16x16x32_bf16(kf11, qa1[tl], z1, 0, 0, 0);
      float p0[4], p1[4];
      #pragma unroll
      for (int i = 0; i < 4; i++){
        int key0 = kc * 32 + qd * 4 + i;
        int key1 = key0 + 16;
        float s0 = z0[i] * 0.125f, s1 = z1[i] * 0.125f;
        if (qp[tl]){ s0 = -1.0e9f; s1 = -1.0e9f; }
        p0[i] = (key0 < 360) ? __expf(s0 - mrun[tl]) : 0.0f;
        p1[i] = (key1 < 360) ? __expf(s1 - mrun[tl]) : 0.0f;
        lsum[tl] += p0[i] + p1[i];
      }
      *(uint2*)(&Pb[wave][r][qd * 4])      = make_uint2(pack2(p0[0], p0[1]), pack2(p0[2], p0[3]));
      *(uint2*)(&Pb[wave][r][16 + qd * 4]) = make_uint2(pack2(p1[0], p1[1]), pack2(p1[2], p1[3]));
      asm volatile("s_waitcnt lgkmcnt(0)" ::: "memory");
      frag8 pa = *(const frag8*)(&Pb[wave][r][qd * 8]);   // A[m=query r][k=key32]
      #pragma unroll
      for (int dt = 0; dt < 4; dt++)
        accO[tl][dt] = __builtin_amdgcn_mfma_f32_16x16x32_bf16(pa, vf[dt], accO[tl][dt], 0, 0, 0);
      asm volatile("s_waitcnt lgkmcnt(0)" ::: "memory");  // pa consumed before next tile's writes
    }
  }

  // ---- epilogue ----
  for (int tl = 0; tl < ntile; tl++){
    int qt = wave * 6 + tl;
    float ls = lsum[tl];
    ls += __shfl_xor(ls, 16, 64);
    ls += __shfl_xor(ls, 32, 64);
    float invl = 1.0f / ls;                 // for query r (uniform over qd)
    #pragma unroll
    for (int i = 0; i < 4; i++){
      float inv_i = __shfl(invl, qd * 4 + i, 64);
      int qglob = qt * 16 + qd * 4 + i;     // C row = query qd*4+i, col = d
      if (qglob < 360){
        #pragma unroll
        for (int dt = 0; dt < 4; dt++)
          ctx[((size_t)(b * 360 + qglob)) * 256 + h * 64 + dt * 16 + r] =
              __float2bfloat16(accO[tl][dt][i] * inv_i);
      }
    }
  }
}

// head: one wave per (b, pair). 5824 blocks x 4 waves = 23296 = 256*91.
__global__ __launch_bounds__(256) void head_k(
    const bf16* __restrict__ x, const int* __restrict__ src,
    const float* __restrict__ wl, const float* __restrict__ bl,
    float* __restrict__ out)
{
  int widx = blockIdx.x * 4 + (threadIdx.x >> 6);
  if (widx >= 23296) return;
  int lane = threadIdx.x & 63;
  int b = widx / 91, p = widx - b * 91;

  int i = 0, rem = p;
  while (rem >= 13 - i){ rem -= 13 - i; i++; }
  int j = i + 1 + rem;
  int base = 12 * i - (i * (i - 1)) / 2;
  int pe = base + (j - i) - 1;
  int eb = 28 + 2 * pe;

  int g = lane >> 3, sub = lane & 7;
  int idxg;
  if (g == 0) idxg = 2 * i;
  else if (g == 1) idxg = 2 * i + 1;
  else if (g == 2) idxg = 2 * j;
  else if (g == 3) idxg = 2 * j + 1;
  else idxg = eb + (g - 4);
  bool zm = !(g >= 4 && j == 13);

  float a0 = 0.f, a1 = 0.f, a2 = 0.f;
  if (zm){
    const bf16* xr = x + ((size_t)b * 360 + idxg) * 256 + sub * 32;
    const float* wr = wl + (size_t)(g * 256 + sub * 32) * 3;
    #pragma unroll
    for (int t = 0; t < 32; t++){
      float f = __bfloat162float(xr[t]);
      a0 += f * wr[t * 3 + 0];
      a1 += f * wr[t * 3 + 1];
      a2 += f * wr[t * 3 + 2];
    }
  }
  #pragma unroll
  for (int o = 1; o < 64; o <<= 1){
    a0 += __shfl_xor(a0, o, 64);
    a1 += __shfl_xor(a1, o, 64);
    a2 += __shfl_xor(a2, o, 64);
  }
  if (lane == 0){
    const int* sr = src + b * 360;
    int ti = sr[2 * i], ai = sr[2 * i + 1], tj = sr[2 * j], aj = sr[2 * j + 1];
    bool c1 = (ai == 2) || (aj == 2);
    bool c2 = (tj == 1) || (ai == 1) || (aj == 1);
    bool c3 = (ti == 799) || (tj == 799) || (ai == 0) || (aj == 0);
    bool c4 = false;
    if (j < 13){
      int es = 28 + 4 * pe;
      c4 = (sr[es] == 1) || (sr[es + 1] == 1) || (sr[es + 2] == 1) || (sr[es + 3] == 1);
    }
    bool m1 = c3 || c4, m2 = m1 || c2, m3 = m2 || c1;
    float* op = out + ((size_t)b * 91 + p) * 3;
    op[0] = m1 ? -1.0e9f : (a0 + bl[0]);
    op[1] = m2 ? -1.0e9f : (a1 + bl[1]);
    op[2] = m3 ? -1.0e9f : (a2 + bl[2]);
  }
}

extern "C" void kernel_launch(void* const* d_in, const int* in_sizes, int n_in,
                              void* d_out, int out_size, void* d_ws, size_t ws_size,
                              hipStream_t stream)
{
  const int*   src = (const int*)  d_in[0];
  const float* emb = (const float*)d_in[1];
  const float* wq  = (const float*)d_in[2];  const float* bq = (const float*)d_in[3];
  const float* wk  = (const float*)d_in[4];  const float* bk = (const float*)d_in[5];
  const float* wv  = (const float*)d_in[6];  const float* bv = (const float*)d_in[7];
  const float* wo  = (const float*)d_in[8];  const float* bo = (const float*)d_in[9];
  const float* n1a = (const float*)d_in[10]; const float* n1b = (const float*)d_in[11];
  const float* n2a = (const float*)d_in[12]; const float* n2b = (const float*)d_in[13];
  const float* w1  = (const float*)d_in[14]; const float* b1 = (const float*)d_in[15];
  const float* w2  = (const float*)d_in[16]; const float* b2 = (const float*)d_in[17];
  const float* wl  = (const float*)d_in[18]; const float* bl = (const float*)d_in[19];
  float* out = (float*)d_out;

  if (ws_size < 191365120ull) return;

  char* ws = (char*)d_ws;
  bf16* x   = (bf16*)(ws);                    // [92160][256]
  bf16* xn  = (bf16*)(ws + 47185920ull);      // [92160][256]
  char* R   = ws + 94371840ull;
  bf16* qh   = (bf16*)(R);                    // [512][360][64]
  bf16* kh   = (bf16*)(R + 23592960ull);
  bf16* vth  = (bf16*)(R + 47185920ull);      // [512][64][360]
  bf16* ctxh = (bf16*)(R + 70778880ull);      // [46080][256]
  bf16* hbuf = (bf16*)(R);                    // ffn phase: [92160][512]
  bf16* wT   = (bf16*)(ws + 188743680ull);
  bf16* wqT = wT;
  bf16* wkT = wT + 65536;
  bf16* wvT = wT + 131072;
  bf16* woT = wT + 196608;
  bf16* w1T = wT + 262144;       // [2048][256]
  bf16* w2T = w1T + 524288;      // [256][2048]

  cvt_transpose<<<256, 256, 0, stream>>>(wqT, wq, 256, 256);
  cvt_transpose<<<256, 256, 0, stream>>>(wkT, wk, 256, 256);
  cvt_transpose<<<256, 256, 0, stream>>>(wvT, wv, 256, 256);
  cvt_transpose<<<256, 256, 0, stream>>>(woT, wo, 256, 256);
  cvt_transpose<<<2048, 256, 0, stream>>>(w1T, w1, 256, 2048);
  cvt_transpose<<<2048, 256, 0, stream>>>(w2T, w2, 2048, 256);

  embed_ln1<<<23040, 256, 0, stream>>>(src, emb, n1a, n1b, x, xn);

  dim3 gqkv(360, 6), gh(360, 2), g2(720, 2), g4(720, 4);
  for (int half = 0; half < 2; half++){
    size_t ro = (size_t)half * 46080;
    const bf16* xnh = xn + ro * 256;
    gemm_bt<4><<<gqkv, 256, 0, stream>>>(xnh, 256, wqT, 256, nullptr, qh, nullptr,
                                         768, 256, bq, bk, bv);
    attn3<<<512, 256, 0, stream>>>(qh, kh, vth, src + ro, ctxh);
    gemm_bt<3><<<gh, 256, 0, stream>>>(ctxh, 256, woT, 256, bo, nullptr, x + ro * 256,
                                       256, 256, nullptr, nullptr, nullptr);
  }

  ln_k<<<23040, 256, 0, stream>>>(x, n2a, n2b, xn);

  for (int c = 0; c < 4; c++){
    gemm_bt<2><<<g4, 256, 0, stream>>>(xn, 256, w1T + (size_t)c * 512 * 256, 256,
                                       b1 + c * 512, hbuf, nullptr, 512, 256,
                                       nullptr, nullptr, nullptr);
    gemm_bt<3><<<g2, 256, 0, stream>>>(hbuf, 512, w2T + (size_t)c * 512, 2048,
                                       (c == 0 ? b2 : nullptr), nullptr, x, 256, 512,
                                       nullptr, nullptr, nullptr);
  }

  head_k<<<5824, 256, 0, stream>>>(x, src, wl, bl, out);
}

// Round 5
// 953.886 us; speedup vs baseline: 1.6991x; 1.6991x over previous
//
#include <hip/hip_runtime.h>
#include <hip/hip_bf16.h>
#include <math.h>

// ---------------------------------------------------------------------------
// Round 4: attn4 = single-pass (no-max) flash attn, 512 thr / 8 waves,
// 3 q-tiles per wave with FIXED unrolled loops (R3's attn3 spilled: runtime
// ntile bound -> arrays in scratch -> 700MB WRITE_SIZE). K in LDS stride 72.
// FFN re-chunked along M: h_chunk [23040][2048] = R region; xn read 1x,
// x residual rmw 1x, FFN2 K=2048.
// ws layout unchanged (191,365,120 B).
// ---------------------------------------------------------------------------

using bf16 = __hip_bfloat16;
typedef __attribute__((ext_vector_type(8))) short frag8;
typedef __attribute__((ext_vector_type(4))) float f32x4;

static __device__ __forceinline__ float wave_sum64(float v){
  #pragma unroll
  for (int o = 32; o >= 1; o >>= 1) v += __shfl_xor(v, o, 64);
  return v;
}

static __device__ __forceinline__ void gl_lds16(const bf16* g, bf16* l){
  __builtin_amdgcn_global_load_lds((const __attribute__((address_space(1))) void*)g,
                                   (__attribute__((address_space(3))) void*)l, 16, 0, 0);
}

static __device__ __forceinline__ unsigned pack2(float a, float b){
  union { bf16 h[2]; unsigned u; } u;
  u.h[0] = __float2bfloat16(a); u.h[1] = __float2bfloat16(b);
  return u.u;
}

// dst[n*K+k] = (bf16) src[k*N+n]
__global__ __launch_bounds__(256) void cvt_transpose(bf16* __restrict__ dst,
                                                     const float* __restrict__ src,
                                                     int K, int N){
  int idx = blockIdx.x * 256 + threadIdx.x;
  if (idx >= K * N) return;
  int n = idx / K, k = idx - n * K;
  dst[idx] = __float2bfloat16(src[(size_t)k * N + n]);
}

// embed + PE + scale -> x (bf16), LN1 -> xn (bf16). one wave/row, grid 23040.
__global__ __launch_bounds__(256) void embed_ln1(
    const int* __restrict__ src, const float* __restrict__ emb,
    const float* __restrict__ na, const float* __restrict__ nb,
    bf16* __restrict__ x, bf16* __restrict__ xn)
{
  int row  = blockIdx.x * 4 + (threadIdx.x >> 6);
  int lane = threadIdx.x & 63;
  int s = row % 360;
  int tok = src[row];
  float4 v = *(const float4*)(emb + (size_t)tok * 256 + lane * 4);
  float vv[4] = {v.x, v.y, v.z, v.w};
  if (s < 340){
    const float C = (-2.0f / 256.0f) * 13.287712379549449f;  // -2/D * log2(10000)
    #pragma unroll
    for (int t = 0; t < 4; t++){
      int c = lane * 4 + t;
      float ang = (float)s * exp2f(C * (float)c);
      float pe = (c & 1) ? cosf(ang) : sinf(ang);
      vv[t] = 16.0f * vv[t] + pe;
    }
  }
  float sum = wave_sum64(vv[0] + vv[1] + vv[2] + vv[3]);
  float mu = sum * (1.0f / 256.0f);
  float d0 = vv[0]-mu, d1 = vv[1]-mu, d2 = vv[2]-mu, d3 = vv[3]-mu;
  float sq = wave_sum64(d0*d0 + d1*d1 + d2*d2 + d3*d3);
  float inv = 1.0f / (sqrtf(sq * (1.0f / 255.0f)) + 1e-6f);
  bf16 xo[4] = { __float2bfloat16(vv[0]), __float2bfloat16(vv[1]),
                 __float2bfloat16(vv[2]), __float2bfloat16(vv[3]) };
  *(uint2*)(x + (size_t)row * 256 + lane * 4) = *(uint2*)xo;
  float4 a4 = *(const float4*)(na + lane * 4);
  float4 b4 = *(const float4*)(nb + lane * 4);
  bf16 o4[4] = { __float2bfloat16(a4.x * d0 * inv + b4.x),
                 __float2bfloat16(a4.y * d1 * inv + b4.y),
                 __float2bfloat16(a4.z * d2 * inv + b4.z),
                 __float2bfloat16(a4.w * d3 * inv + b4.w) };
  *(uint2*)(xn + (size_t)row * 256 + lane * 4) = *(uint2*)o4;
}

// LN over bf16 x -> bf16 xn. one wave per row. grid 23040.
__global__ __launch_bounds__(256) void ln_k(
    const bf16* __restrict__ x, const float* __restrict__ na,
    const float* __restrict__ nb, bf16* __restrict__ xn)
{
  int row  = blockIdx.x * 4 + (threadIdx.x >> 6);
  int lane = threadIdx.x & 63;
  uint2 raw = *(const uint2*)(x + (size_t)row * 256 + lane * 4);
  bf16* xr = (bf16*)&raw;
  float v0 = __bfloat162float(xr[0]), v1 = __bfloat162float(xr[1]);
  float v2 = __bfloat162float(xr[2]), v3 = __bfloat162float(xr[3]);
  float sum = wave_sum64(v0 + v1 + v2 + v3);
  float mu = sum * (1.0f / 256.0f);
  float d0 = v0-mu, d1 = v1-mu, d2 = v2-mu, d3 = v3-mu;
  float sq = wave_sum64(d0*d0 + d1*d1 + d2*d2 + d3*d3);
  float inv = 1.0f / (sqrtf(sq * (1.0f / 255.0f)) + 1e-6f);
  float4 a4 = *(const float4*)(na + lane * 4);
  float4 b4 = *(const float4*)(nb + lane * 4);
  bf16 o4[4] = { __float2bfloat16(a4.x * d0 * inv + b4.x),
                 __float2bfloat16(a4.y * d1 * inv + b4.y),
                 __float2bfloat16(a4.z * d2 * inv + b4.z),
                 __float2bfloat16(a4.w * d3 * inv + b4.w) };
  *(uint2*)(xn + (size_t)row * 256 + lane * 4) = *(uint2*)o4;
}

// C = A[M][K] @ Bt[N][K]^T + bias. 128x128 tile, BK=32, global_load_lds staging.
// MODE 2: relu, bf16 row-major [M][N]
// MODE 3: bf16 residual in-place: xres[m*256+n] += acc (+bias)
// MODE 4: merged QKV epilogue (N=768): n<256 q-layout, <512 k-layout, else v^T
template<int MODE>
__global__ __launch_bounds__(256) void gemm_bt(
    const bf16* __restrict__ A, int lda,
    const bf16* __restrict__ Bt, int ldb,
    const float* __restrict__ bias,
    bf16* __restrict__ outb, bf16* __restrict__ xres,
    int N, int K,
    const float* __restrict__ bq, const float* __restrict__ bk,
    const float* __restrict__ bv)
{
  __shared__ bf16 As[128 * 32];
  __shared__ bf16 Bs[128 * 32];
  int m0 = blockIdx.x * 128, n0 = blockIdx.y * 128;
  int tid = threadIdx.x;
  int wave = tid >> 6, lane = tid & 63;
  int wm = (wave >> 1) * 64, wn = (wave & 1) * 64;
  int r = lane & 15, qd = lane >> 4;

  int slot0 = wave * 128 + lane;
  int row0 = slot0 >> 2, c0 = slot0 & 3;
  int row1 = (slot0 + 64) >> 2, c1 = (slot0 + 64) & 3;
  const bf16* ag0 = A  + (size_t)(m0 + row0) * lda + c0 * 8;
  const bf16* ag1 = A  + (size_t)(m0 + row1) * lda + c1 * 8;
  const bf16* bg0 = Bt + (size_t)(n0 + row0) * ldb + c0 * 8;
  const bf16* bg1 = Bt + (size_t)(n0 + row1) * ldb + c1 * 8;
  bf16* lA0 = As + (size_t)(wave * 128) * 8;
  bf16* lA1 = As + (size_t)(wave * 128 + 64) * 8;
  bf16* lB0 = Bs + (size_t)(wave * 128) * 8;
  bf16* lB1 = Bs + (size_t)(wave * 128 + 64) * 8;

  f32x4 acc[4][4];
  #pragma unroll
  for (int mt = 0; mt < 4; mt++)
    #pragma unroll
    for (int nt = 0; nt < 4; nt++) acc[mt][nt] = (f32x4){0.f, 0.f, 0.f, 0.f};

  for (int k0 = 0; k0 < K; k0 += 32){
    gl_lds16(ag0, lA0); gl_lds16(ag1, lA1);
    gl_lds16(bg0, lB0); gl_lds16(bg1, lB1);
    ag0 += 32; ag1 += 32; bg0 += 32; bg1 += 32;
    __syncthreads();
    frag8 af[4], bfr[4];
    #pragma unroll
    for (int t = 0; t < 4; t++){
      af[t]  = *(const frag8*)(As + (wm + t * 16 + r) * 32 + qd * 8);
      bfr[t] = *(const frag8*)(Bs + (wn + t * 16 + r) * 32 + qd * 8);
    }
    #pragma unroll
    for (int mt = 0; mt < 4; mt++)
      #pragma unroll
      for (int nt = 0; nt < 4; nt++)
        acc[mt][nt] = __builtin_amdgcn_mfma_f32_16x16x32_bf16(af[mt], bfr[nt], acc[mt][nt], 0, 0, 0);
    __syncthreads();
  }

  #pragma unroll
  for (int mt = 0; mt < 4; mt++)
    #pragma unroll
    for (int nt = 0; nt < 4; nt++)
      #pragma unroll
      for (int i = 0; i < 4; i++){
        int m = m0 + wm + mt * 16 + qd * 4 + i;
        int n = n0 + wn + nt * 16 + r;
        float v = acc[mt][nt][i];
        if (MODE == 2){
          v += bias[n];
          v = fmaxf(v, 0.0f);
          outb[(size_t)m * N + n] = __float2bfloat16(v);
        } else if (MODE == 3){
          if (bias) v += bias[n];
          size_t o = (size_t)m * 256 + n;
          xres[o] = __float2bfloat16(__bfloat162float(xres[o]) + v);
        } else {  // MODE 4
          int region = n >> 8, nn = n & 255;
          int h = nn >> 6, dk = nn & 63;
          v += (region == 0 ? bq : region == 1 ? bk : bv)[nn];
          int b = m / 360, s = m - b * 360;
          if (region < 2){
            size_t off = (((size_t)(b * 4 + h) * 360 + s) << 6) + dk;
            outb[off + (size_t)region * 11796480] = __float2bfloat16(v);
          } else {
            outb[23592960 + ((size_t)((b * 4 + h) * 64 + dk)) * 360 + s] = __float2bfloat16(v);
          }
        }
      }
}

// attn4: one block per (b_local,h), 512 thr / 8 waves, 3 q-tiles/wave
// (qt = wave*3+tl, tile 23 inactive). Single-pass softmax (no max: scores O(1);
// pad queries use s=0 -> uniform, matching reference). K LDS-resident.
__global__ __launch_bounds__(512) void attn4(
    const bf16* __restrict__ q, const bf16* __restrict__ kk, const bf16* __restrict__ vt,
    const int* __restrict__ src, bf16* __restrict__ ctx)
{
  __shared__ bf16 Ks[360][72];      // 51840 B, stride 72: 2-way banks (free)
  __shared__ bf16 Pb[8][16][48];    // 12288 B
  int bh = blockIdx.x;
  int b = bh >> 2, h = bh & 3;
  int wave = threadIdx.x >> 6, lane = threadIdx.x & 63;
  int r = lane & 15, qd = lane >> 4;
  const bf16* qb = q  + (size_t)bh * 360 * 64;
  const bf16* kb = kk + (size_t)bh * 360 * 64;
  const bf16* vb = vt + (size_t)bh * 64 * 360;
  const int* srow = src + b * 360;

  for (int c = threadIdx.x; c < 2880; c += 512){
    int row = c >> 3, g = c & 7;
    *(uint4*)(&Ks[row][g * 8]) = *(const uint4*)(kb + row * 64 + g * 8);
  }
  __syncthreads();

  frag8 qa0[3], qa1[3];
  bool qp[3];
  float lsum[3];
  f32x4 accO[3][4];
  #pragma unroll
  for (int tl = 0; tl < 3; tl++){
    int qt = wave * 3 + tl;
    int qg = qt * 16 + r;
    int qrow = qg > 359 ? 359 : qg;
    qa0[tl] = *(const frag8*)(qb + qrow * 64 + qd * 8);
    qa1[tl] = *(const frag8*)(qb + qrow * 64 + 32 + qd * 8);
    qp[tl] = (qg < 360) && (srow[qg] == 799);
    lsum[tl] = 0.f;
    #pragma unroll
    for (int dt = 0; dt < 4; dt++) accO[tl][dt] = (f32x4){0.f, 0.f, 0.f, 0.f};
  }

  for (int kc = 0; kc < 12; kc++){
    int krow0 = kc * 32 + r;      if (krow0 > 359) krow0 = 359;
    int krow1 = kc * 32 + 16 + r; if (krow1 > 359) krow1 = 359;
    frag8 kf00 = *(const frag8*)(&Ks[krow0][qd * 8]);
    frag8 kf01 = *(const frag8*)(&Ks[krow0][32 + qd * 8]);
    frag8 kf10 = *(const frag8*)(&Ks[krow1][qd * 8]);
    frag8 kf11 = *(const frag8*)(&Ks[krow1][32 + qd * 8]);
    frag8 vf[4];
    #pragma unroll
    for (int dt = 0; dt < 4; dt++)
      vf[dt] = *(const frag8*)(vb + (size_t)(dt * 16 + r) * 360 + kc * 32 + qd * 8);

    #pragma unroll
    for (int tl = 0; tl < 3; tl++){
      f32x4 z0 = {0.f, 0.f, 0.f, 0.f}, z1 = {0.f, 0.f, 0.f, 0.f};
      z0 = __builtin_amdgcn_mfma_f32_16x16x32_bf16(kf00, qa0[tl], z0, 0, 0, 0);  // C[key][query=r]
      z0 = __builtin_amdgcn_mfma_f32_16x16x32_bf16(kf01, qa1[tl], z0, 0, 0, 0);
      z1 = __builtin_amdgcn_mfma_f32_16x16x32_bf16(kf10, qa0[tl], z1, 0, 0, 0);
      z1 = __builtin_amdgcn_mfma_f32_16x16x32_bf16(kf11, qa1[tl], z1, 0, 0, 0);
      float p0[4], p1[4];
      #pragma unroll
      for (int i = 0; i < 4; i++){
        int key0 = kc * 32 + qd * 4 + i;
        int key1 = key0 + 16;
        float s0 = z0[i] * 0.125f, s1 = z1[i] * 0.125f;
        if (qp[tl]){ s0 = 0.0f; s1 = 0.0f; }      // uniform softmax for PAD queries
        p0[i] = (key0 < 360) ? __expf(s0) : 0.0f;
        p1[i] = (key1 < 360) ? __expf(s1) : 0.0f;
        lsum[tl] += p0[i] + p1[i];
      }
      *(uint2*)(&Pb[wave][r][qd * 4])      = make_uint2(pack2(p0[0], p0[1]), pack2(p0[2], p0[3]));
      *(uint2*)(&Pb[wave][r][16 + qd * 4]) = make_uint2(pack2(p1[0], p1[1]), pack2(p1[2], p1[3]));
      asm volatile("s_waitcnt lgkmcnt(0)" ::: "memory");
      frag8 pa = *(const frag8*)(&Pb[wave][r][qd * 8]);   // A[m=query r][k=key32]
      #pragma unroll
      for (int dt = 0; dt < 4; dt++)
        accO[tl][dt] = __builtin_amdgcn_mfma_f32_16x16x32_bf16(pa, vf[dt], accO[tl][dt], 0, 0, 0);
      asm volatile("s_waitcnt lgkmcnt(0)" ::: "memory");  // pa consumed before next tl's writes
    }
  }

  #pragma unroll
  for (int tl = 0; tl < 3; tl++){
    int qt = wave * 3 + tl;
    float ls = lsum[tl];
    ls += __shfl_xor(ls, 16, 64);
    ls += __shfl_xor(ls, 32, 64);
    float invl = 1.0f / ls;                 // for query r
    #pragma unroll
    for (int i = 0; i < 4; i++){
      float inv_i = __shfl(invl, qd * 4 + i, 64);
      int qglob = qt * 16 + qd * 4 + i;
      if (qglob < 360){
        #pragma unroll
        for (int dt = 0; dt < 4; dt++)
          ctx[((size_t)(b * 360 + qglob)) * 256 + h * 64 + dt * 16 + r] =
              __float2bfloat16(accO[tl][dt][i] * inv_i);
      }
    }
  }
}

// head: one wave per (b, pair). 5824 blocks x 4 waves = 23296 = 256*91.
__global__ __launch_bounds__(256) void head_k(
    const bf16* __restrict__ x, const int* __restrict__ src,
    const float* __restrict__ wl, const float* __restrict__ bl,
    float* __restrict__ out)
{
  int widx = blockIdx.x * 4 + (threadIdx.x >> 6);
  if (widx >= 23296) return;
  int lane = threadIdx.x & 63;
  int b = widx / 91, p = widx - b * 91;

  int i = 0, rem = p;
  while (rem >= 13 - i){ rem -= 13 - i; i++; }
  int j = i + 1 + rem;
  int base = 12 * i - (i * (i - 1)) / 2;
  int pe = base + (j - i) - 1;
  int eb = 28 + 2 * pe;

  int g = lane >> 3, sub = lane & 7;
  int idxg;
  if (g == 0) idxg = 2 * i;
  else if (g == 1) idxg = 2 * i + 1;
  else if (g == 2) idxg = 2 * j;
  else if (g == 3) idxg = 2 * j + 1;
  else idxg = eb + (g - 4);
  bool zm = !(g >= 4 && j == 13);

  float a0 = 0.f, a1 = 0.f, a2 = 0.f;
  if (zm){
    const bf16* xr = x + ((size_t)b * 360 + idxg) * 256 + sub * 32;
    const float* wr = wl + (size_t)(g * 256 + sub * 32) * 3;
    #pragma unroll
    for (int t = 0; t < 32; t++){
      float f = __bfloat162float(xr[t]);
      a0 += f * wr[t * 3 + 0];
      a1 += f * wr[t * 3 + 1];
      a2 += f * wr[t * 3 + 2];
    }
  }
  #pragma unroll
  for (int o = 1; o < 64; o <<= 1){
    a0 += __shfl_xor(a0, o, 64);
    a1 += __shfl_xor(a1, o, 64);
    a2 += __shfl_xor(a2, o, 64);
  }
  if (lane == 0){
    const int* sr = src + b * 360;
    int ti = sr[2 * i], ai = sr[2 * i + 1], tj = sr[2 * j], aj = sr[2 * j + 1];
    bool c1 = (ai == 2) || (aj == 2);
    bool c2 = (tj == 1) || (ai == 1) || (aj == 1);
    bool c3 = (ti == 799) || (tj == 799) || (ai == 0) || (aj == 0);
    bool c4 = false;
    if (j < 13){
      int es = 28 + 4 * pe;
      c4 = (sr[es] == 1) || (sr[es + 1] == 1) || (sr[es + 2] == 1) || (sr[es + 3] == 1);
    }
    bool m1 = c3 || c4, m2 = m1 || c2, m3 = m2 || c1;
    float* op = out + ((size_t)b * 91 + p) * 3;
    op[0] = m1 ? -1.0e9f : (a0 + bl[0]);
    op[1] = m2 ? -1.0e9f : (a1 + bl[1]);
    op[2] = m3 ? -1.0e9f : (a2 + bl[2]);
  }
}

extern "C" void kernel_launch(void* const* d_in, const int* in_sizes, int n_in,
                              void* d_out, int out_size, void* d_ws, size_t ws_size,
                              hipStream_t stream)
{
  const int*   src = (const int*)  d_in[0];
  const float* emb = (const float*)d_in[1];
  const float* wq  = (const float*)d_in[2];  const float* bq = (const float*)d_in[3];
  const float* wk  = (const float*)d_in[4];  const float* bk = (const float*)d_in[5];
  const float* wv  = (const float*)d_in[6];  const float* bv = (const float*)d_in[7];
  const float* wo  = (const float*)d_in[8];  const float* bo = (const float*)d_in[9];
  const float* n1a = (const float*)d_in[10]; const float* n1b = (const float*)d_in[11];
  const float* n2a = (const float*)d_in[12]; const float* n2b = (const float*)d_in[13];
  const float* w1  = (const float*)d_in[14]; const float* b1 = (const float*)d_in[15];
  const float* w2  = (const float*)d_in[16]; const float* b2 = (const float*)d_in[17];
  const float* wl  = (const float*)d_in[18]; const float* bl = (const float*)d_in[19];
  float* out = (float*)d_out;

  if (ws_size < 191365120ull) return;

  char* ws = (char*)d_ws;
  bf16* x   = (bf16*)(ws);                    // [92160][256]
  bf16* xn  = (bf16*)(ws + 47185920ull);      // [92160][256]
  char* R   = ws + 94371840ull;
  bf16* qh   = (bf16*)(R);                    // [512][360][64]
  bf16* kh   = (bf16*)(R + 23592960ull);
  bf16* vth  = (bf16*)(R + 47185920ull);      // [512][64][360]
  bf16* ctxh = (bf16*)(R + 70778880ull);      // [46080][256]
  bf16* hbuf = (bf16*)(R);                    // ffn phase: [23040][2048] per M-chunk
  bf16* wT   = (bf16*)(ws + 188743680ull);
  bf16* wqT = wT;
  bf16* wkT = wT + 65536;
  bf16* wvT = wT + 131072;
  bf16* woT = wT + 196608;
  bf16* w1T = wT + 262144;       // [2048][256]
  bf16* w2T = w1T + 524288;      // [256][2048]

  cvt_transpose<<<256, 256, 0, stream>>>(wqT, wq, 256, 256);
  cvt_transpose<<<256, 256, 0, stream>>>(wkT, wk, 256, 256);
  cvt_transpose<<<256, 256, 0, stream>>>(wvT, wv, 256, 256);
  cvt_transpose<<<256, 256, 0, stream>>>(woT, wo, 256, 256);
  cvt_transpose<<<2048, 256, 0, stream>>>(w1T, w1, 256, 2048);
  cvt_transpose<<<2048, 256, 0, stream>>>(w2T, w2, 2048, 256);

  embed_ln1<<<23040, 256, 0, stream>>>(src, emb, n1a, n1b, x, xn);

  dim3 gqkv(360, 6), gh(360, 2);
  for (int half = 0; half < 2; half++){
    size_t ro = (size_t)half * 46080;
    const bf16* xnh = xn + ro * 256;
    gemm_bt<4><<<gqkv, 256, 0, stream>>>(xnh, 256, wqT, 256, nullptr, qh, nullptr,
                                         768, 256, bq, bk, bv);
    attn4<<<512, 512, 0, stream>>>(qh, kh, vth, src + ro, ctxh);
    gemm_bt<3><<<gh, 256, 0, stream>>>(ctxh, 256, woT, 256, bo, nullptr, x + ro * 256,
                                       256, 256, nullptr, nullptr, nullptr);
  }

  ln_k<<<23040, 256, 0, stream>>>(x, n2a, n2b, xn);

  // FFN chunked along M: 4 chunks of 23040 rows; h full-width [23040][2048].
  for (int mc = 0; mc < 4; mc++){
    const bf16* xnc = xn + (size_t)mc * 23040 * 256;
    bf16* xc = x + (size_t)mc * 23040 * 256;
    gemm_bt<2><<<dim3(180, 16), 256, 0, stream>>>(xnc, 256, w1T, 256, b1, hbuf, nullptr,
                                                  2048, 256, nullptr, nullptr, nullptr);
    gemm_bt<3><<<dim3(180, 2), 256, 0, stream>>>(hbuf, 2048, w2T, 2048, b2, nullptr, xc,
                                                 256, 2048, nullptr, nullptr, nullptr);
  }

  head_k<<<5824, 256, 0, stream>>>(x, src, wl, bl, out);
}